// Round 3
// baseline (2298.160 us; speedup 1.0000x reference)
//
#include <hip/hip_runtime.h>
#include <cstddef>
#include <cstdint>

typedef unsigned short ushort_t;
typedef __attribute__((ext_vector_type(8))) short short8;
typedef __attribute__((ext_vector_type(4))) float f32x4;

constexpr int D_ = 512, K_ = 8192, N_ = 16384;
constexpr float MARGIN = 0.75f;   // ~15 sigma of bf16 score-noise difference

// RNE float->bf16 (data has no NaN)
__device__ __forceinline__ ushort_t f2bf(float f) {
  unsigned u = __float_as_uint(f);
  return (ushort_t)((u + 0x7FFFu + ((u >> 16) & 1u)) >> 16);
}

__device__ __forceinline__ void gld16(void* l, const void* g) {
  __builtin_amdgcn_global_load_lds((const __attribute__((address_space(1))) void*)g,
                                   (__attribute__((address_space(3))) void*)l, 16, 0, 0);
}

// -------- zero the two worklist counters (runs AFTER dist_mfma; aliases xb) --------
__global__ void init_ws(int* counters) {
  if (threadIdx.x < 2) counters[threadIdx.x] = 0;
}

// -------- convert x -> bf16 --------
__global__ __launch_bounds__(256) void conv_x(const float* __restrict__ x, ushort_t* __restrict__ xb) {
  int t = blockIdx.x * 256 + threadIdx.x;
  const float4* p = (const float4*)x;
  float4 a = p[t * 2], b = p[t * 2 + 1];
  short8 v;
  v[0] = (short)f2bf(a.x); v[1] = (short)f2bf(a.y); v[2] = (short)f2bf(a.z); v[3] = (short)f2bf(a.w);
  v[4] = (short)f2bf(b.x); v[5] = (short)f2bf(b.y); v[6] = (short)f2bf(b.z); v[7] = (short)f2bf(b.w);
  *(short8*)(xb + (size_t)t * 8) = v;
}

// -------- convert embed -> bf16, ehs = 0.5*||e||^2 (fp32) --------
__global__ __launch_bounds__(256) void conv_e(const float* __restrict__ e, ushort_t* __restrict__ eb,
                                              float* __restrict__ ehs) {
  int w = (blockIdx.x * 256 + threadIdx.x) >> 6;
  int l = threadIdx.x & 63;
  const float4* p = (const float4*)(e + (size_t)w * D_);
  float4 a = p[l * 2], b = p[l * 2 + 1];
  float s = a.x * a.x + a.y * a.y + a.z * a.z + a.w * a.w
          + b.x * b.x + b.y * b.y + b.z * b.z + b.w * b.w;
  short8 v;
  v[0] = (short)f2bf(a.x); v[1] = (short)f2bf(a.y); v[2] = (short)f2bf(a.z); v[3] = (short)f2bf(a.w);
  v[4] = (short)f2bf(b.x); v[5] = (short)f2bf(b.y); v[6] = (short)f2bf(b.z); v[7] = (short)f2bf(b.w);
  *(short8*)(eb + (size_t)w * D_ + l * 8) = v;
#pragma unroll
  for (int off = 32; off; off >>= 1) s += __shfl_xor(s, off);
  if (l == 0) ehs[w] = 0.5f * s;
}

// -------- MFMA scoring: per (row, 128-col block) top-2 (+indices) and margin count --------
// grid (N_/128, K_/128), 256 threads (2x2 waves, 64x64 per wave)
__global__ __launch_bounds__(256, 2) void dist_mfma(const ushort_t* __restrict__ xb,
                                                    const ushort_t* __restrict__ eb,
                                                    const float* __restrict__ ehs,
                                                    float4* __restrict__ pp) {
  __shared__ alignas(16) char lds[16384];
  char* As = lds;            // [kq(4)][row(128)] 16B chunks
  char* Bs = lds + 8192;
  const int tid = threadIdx.x, w = tid >> 6, l = tid & 63;
  const int row0 = blockIdx.x * 128, col0 = blockIdx.y * 128;
  const int wr = w >> 1, wc = w & 1;

  f32x4 acc[4][4] = {};
  for (int d0 = 0; d0 < D_; d0 += 32) {
#pragma unroll
    for (int i = 0; i < 2; ++i) {
      gld16(As + w * 2048 + i * 1024, xb + (size_t)(row0 + i * 64 + l) * D_ + d0 + w * 8);
      gld16(Bs + w * 2048 + i * 1024, eb + (size_t)(col0 + i * 64 + l) * D_ + d0 + w * 8);
    }
    __syncthreads();
    short8 a[4], b[4];
#pragma unroll
    for (int i = 0; i < 4; ++i)
      a[i] = *(const short8*)(As + (l >> 4) * 2048 + (wr * 64 + i * 16 + (l & 15)) * 16);
#pragma unroll
    for (int j = 0; j < 4; ++j)
      b[j] = *(const short8*)(Bs + (l >> 4) * 2048 + (wc * 64 + j * 16 + (l & 15)) * 16);
#pragma unroll
    for (int i = 0; i < 4; ++i)
#pragma unroll
      for (int j = 0; j < 4; ++j)
        acc[i][j] = __builtin_amdgcn_mfma_f32_16x16x32_bf16(a[i], b[j], acc[i][j], 0, 0, 0);
    __syncthreads();
  }

  // ---- epilogue: per-row top-2 (with indices) + count within MARGIN of wave top-1 ----
  int colg[4];
  float eh[4];
#pragma unroll
  for (int j = 0; j < 4; ++j) { colg[j] = col0 + wc * 64 + j * 16 + (l & 15); eh[j] = ehs[colg[j]]; }

  const int c = l & 15, g = l >> 4;
  float fs1 = 0.f, fs2 = 0.f;
  int fi1 = 0, fi2 = 0, fcnt = 0;

#pragma unroll
  for (int i = 0; i < 4; ++i) {
    float s1v[4], s2v[4];
    int i1v[4], i2v[4];
#pragma unroll
    for (int r = 0; r < 4; ++r) {
      s1v[r] = -3e38f; s2v[r] = -3e38f; i1v[r] = 0; i2v[r] = 0;
#pragma unroll
      for (int j = 0; j < 4; ++j) {          // ascending cols -> strict '>' keeps min idx
        float v = acc[i][j][r] - eh[j];
        int col = colg[j];
        if (v > s1v[r]) { s2v[r] = s1v[r]; i2v[r] = i1v[r]; s1v[r] = v; i1v[r] = col; }
        else if (v > s2v[r]) { s2v[r] = v; i2v[r] = col; }
      }
    }
    // merge across the 16 col-lanes (xor low 4 bits)
#pragma unroll
    for (int m = 1; m < 16; m <<= 1) {
#pragma unroll
      for (int r = 0; r < 4; ++r) {
        float os1 = __shfl_xor(s1v[r], m), os2 = __shfl_xor(s2v[r], m);
        int oi1 = __shfl_xor(i1v[r], m), oi2 = __shfl_xor(i2v[r], m);
        if (os1 > s1v[r] || (os1 == s1v[r] && oi1 < i1v[r])) {
          if (s1v[r] > os2 || (s1v[r] == os2 && i1v[r] < oi2)) { s2v[r] = s1v[r]; i2v[r] = i1v[r]; }
          else { s2v[r] = os2; i2v[r] = oi2; }
          s1v[r] = os1; i1v[r] = oi1;
        } else {
          if (os1 > s2v[r] || (os1 == s2v[r] && oi1 < i2v[r])) { s2v[r] = os1; i2v[r] = oi1; }
        }
      }
    }
    // conservative count of scores >= wave_top1 - MARGIN (per row), over the wave's 64 cols
    int cv[4];
#pragma unroll
    for (int r = 0; r < 4; ++r) {
      cv[r] = 0;
#pragma unroll
      for (int j = 0; j < 4; ++j)
        cv[r] += (acc[i][j][r] - eh[j] >= s1v[r] - MARGIN) ? 1 : 0;
    }
#pragma unroll
    for (int m = 1; m < 16; m <<= 1)
#pragma unroll
      for (int r = 0; r < 4; ++r) cv[r] += __shfl_xor(cv[r], m);

    // lane (g,c) owns slot c=(i<<2)|r -> row wr*64 + i*16 + g*4 + r
    if ((c >> 2) == i) {
      int rsel = c & 3;
      fs1 = (rsel == 0) ? s1v[0] : (rsel == 1) ? s1v[1] : (rsel == 2) ? s1v[2] : s1v[3];
      fs2 = (rsel == 0) ? s2v[0] : (rsel == 1) ? s2v[1] : (rsel == 2) ? s2v[2] : s2v[3];
      fi1 = (rsel == 0) ? i1v[0] : (rsel == 1) ? i1v[1] : (rsel == 2) ? i1v[2] : i1v[3];
      fi2 = (rsel == 0) ? i2v[0] : (rsel == 1) ? i2v[1] : (rsel == 2) ? i2v[2] : i2v[3];
      fcnt = (rsel == 0) ? cv[0] : (rsel == 1) ? cv[1] : (rsel == 2) ? cv[2] : cv[3];
    }
  }
  const int rib = wr * 64 + (c >> 2) * 16 + g * 4 + (c & 3);

  // cross-wave (wc) merge via LDS (staging area is dead after final __syncthreads)
  float* ss1 = (float*)lds;
  float* ss2 = ss1 + 128;
  int* si1 = (int*)(ss2 + 128);
  int* si2 = si1 + 128;
  int* scnt = si2 + 128;
  if (wc == 1) { ss1[rib] = fs1; ss2[rib] = fs2; si1[rib] = fi1; si2[rib] = fi2; scnt[rib] = fcnt; }
  __syncthreads();
  if (wc == 0) {
    float os1 = ss1[rib], os2 = ss2[rib];
    int oi1 = si1[rib], oi2 = si2[rib], ocnt = scnt[rib];
    if (os1 > fs1 || (os1 == fs1 && oi1 < fi1)) {
      if (fs1 > os2 || (fs1 == os2 && fi1 < oi2)) { fs2 = fs1; fi2 = fi1; }
      else { fs2 = os2; fi2 = oi2; }
      fs1 = os1; fi1 = oi1;
    } else {
      if (os1 > fs2 || (os1 == fs2 && oi1 < fi2)) { fs2 = os1; fi2 = oi1; }
    }
    int cc = fcnt + ocnt; if (cc > 15) cc = 15;
    pp[(size_t)(row0 + rib) * 64 + blockIdx.y] =
        make_float4(fs1, __int_as_float(fi1 | (cc << 16)), fs2, __int_as_float(fi2));
  }
}

// -------- combine partials; decide, or emit candidate list / full-rescore list --------
__global__ __launch_bounds__(256) void combine(const float4* __restrict__ pp,
                                               const float* __restrict__ embed,
                                               float* __restrict__ out,
                                               int* __restrict__ candrows, int* __restrict__ candn,
                                               int* __restrict__ candbuf,
                                               int* __restrict__ fullrows, int* __restrict__ counters) {
  int row = (blockIdx.x * 256 + threadIdx.x) >> 6;
  int l = threadIdx.x & 63;
  float4 v = pp[(size_t)row * 64 + l];
  float s1 = v.x;
  int p1 = __float_as_int(v.y);
  int i1 = p1 & 0xFFFF;
  int cnt = p1 >> 16;
  float s2 = v.z;
  int i2 = __float_as_int(v.w);

  float gs = s1; int gi = i1;
#pragma unroll
  for (int m = 1; m < 64; m <<= 1) {
    float og = __shfl_xor(gs, m);
    int oi = __shfl_xor(gi, m);
    if (og > gs || (og == gs && oi < gi)) { gs = og; gi = oi; }
  }
  float t = gs - MARGIN;
  bool c1 = (s1 >= t);
  bool c2 = (s2 >= t);
  bool ovf = c1 && (cnt >= 3);
  unsigned long long b1 = __ballot(c1);
  unsigned long long b2 = __ballot(c2);
  unsigned long long bo = __ballot(ovf);
  int n1 = __popcll(b1);
  int ncand = n1 + __popcll(b2);

  if (ncand == 1) {
    const float4* src = (const float4*)(embed + (size_t)gi * D_);
    float4* dst = (float4*)(out + (size_t)row * D_);
    dst[l] = src[l];
    dst[l + 64] = src[l + 64];
    if (l == 0) out[(size_t)N_ * D_ + row] = (float)gi;
  } else if (bo == 0ull && ncand <= 16) {
    int slot;
    if (l == 0) slot = atomicAdd(&counters[0], 1);
    slot = __shfl(slot, 0);
    if (l == 0) { candrows[slot] = row; candn[slot] = ncand; }
    unsigned long long below = (1ull << l) - 1ull;
    if (c1) candbuf[slot * 16 + __popcll(b1 & below)] = i1;
    if (c2) candbuf[slot * 16 + n1 + __popcll(b2 & below)] = i2;
  } else {
    if (l == 0) {
      int fs = atomicAdd(&counters[1], 1);
      fullrows[fs] = row;
    }
  }
}

// -------- exact fp32 rescore of candidate columns: one wave per flagged row --------
__global__ __launch_bounds__(256) void cand_rescore(const float* __restrict__ x,
                                                    const float* __restrict__ embed,
                                                    const float* __restrict__ ehs,
                                                    const int* __restrict__ candrows,
                                                    const int* __restrict__ candn,
                                                    const int* __restrict__ candbuf,
                                                    const int* __restrict__ counters,
                                                    float* __restrict__ out) {
  int slot = (blockIdx.x * 256 + threadIdx.x) >> 6;
  int l = threadIdx.x & 63;
  if (slot >= counters[0]) return;
  int row = candrows[slot];
  int nc = candn[slot];
  float4 xa = *(const float4*)(x + (size_t)row * D_ + l * 8);
  float4 xc = *(const float4*)(x + (size_t)row * D_ + l * 8 + 4);
  float bs = -3e38f;
  int bi = 0x7fffffff;
  for (int cI = 0; cI < nc; ++cI) {
    int col = candbuf[slot * 16 + cI];
    float4 ea = *(const float4*)(embed + (size_t)col * D_ + l * 8);
    float4 ec = *(const float4*)(embed + (size_t)col * D_ + l * 8 + 4);
    float s = xa.x * ea.x + xa.y * ea.y + xa.z * ea.z + xa.w * ea.w
            + xc.x * ec.x + xc.y * ec.y + xc.z * ec.z + xc.w * ec.w;
#pragma unroll
    for (int m = 1; m < 64; m <<= 1) s += __shfl_xor(s, m);
    s -= ehs[col];
    if (s > bs || (s == bs && col < bi)) { bs = s; bi = col; }
  }
  const float4* src = (const float4*)(embed + (size_t)bi * D_);
  float4* dst = (float4*)(out + (size_t)row * D_);
  dst[l] = src[l];
  dst[l + 64] = src[l + 64];
  if (l == 0) out[(size_t)N_ * D_ + row] = (float)bi;
}

// -------- full fp32 rescore for overflow rows (expected ~0 rows) --------
__global__ __launch_bounds__(256) void fb_full(const float* __restrict__ x,
                                               const float* __restrict__ embed,
                                               const float* __restrict__ ehs,
                                               const int* __restrict__ fullrows,
                                               const int* __restrict__ counters,
                                               float* __restrict__ out) {
  int nfull = counters[1];
  __shared__ float xs[512];
  __shared__ unsigned long long red[4];
  for (int s = blockIdx.x; s < nfull; s += gridDim.x) {
    int row = fullrows[s];
    __syncthreads();
    for (int q = threadIdx.x; q < 128; q += 256)
      ((float4*)xs)[q] = ((const float4*)(x + (size_t)row * D_))[q];
    __syncthreads();
    float b = -3e38f;
    int bi = 0;
    for (int c0 = 0; c0 < K_; c0 += 256) {
      int col = c0 + threadIdx.x;
      float acc = 0.f;
      for (int d = 0; d < D_; d += 4) {
        float4 ev = *(const float4*)(embed + (size_t)col * D_ + d);
        float4 xv = *(const float4*)(&xs[d]);
        acc = fmaf(ev.x, xv.x, acc);
        acc = fmaf(ev.y, xv.y, acc);
        acc = fmaf(ev.z, xv.z, acc);
        acc = fmaf(ev.w, xv.w, acc);
      }
      float sc = acc - ehs[col];
      if (sc > b) { b = sc; bi = col; }   // ascending cols per thread -> min idx on ties
    }
    unsigned ub = __float_as_uint(b);
    unsigned mb = (ub & 0x80000000u) ? ~ub : (ub | 0x80000000u);
    unsigned long long packed = ((unsigned long long)mb << 32) | (0xFFFFFFFFu - (unsigned)bi);
#pragma unroll
    for (int m = 1; m < 64; m <<= 1) {
      unsigned long long o = __shfl_xor(packed, m);
      if (o > packed) packed = o;
    }
    if ((threadIdx.x & 63) == 0) red[threadIdx.x >> 6] = packed;
    __syncthreads();
    if (threadIdx.x < 64) {
      unsigned long long p0 = red[0] > red[1] ? red[0] : red[1];
      unsigned long long p1 = red[2] > red[3] ? red[2] : red[3];
      unsigned long long p = p0 > p1 ? p0 : p1;
      int idx = (int)(0xFFFFFFFFu - (unsigned)(p & 0xFFFFFFFFu));
      int l = threadIdx.x;
      const float4* src = (const float4*)(embed + (size_t)idx * D_);
      float4* dst = (float4*)(out + (size_t)row * D_);
      dst[l] = src[l];
      dst[l + 64] = src[l + 64];
      if (l == 0) out[(size_t)N_ * D_ + row] = (float)idx;
    }
  }
}

extern "C" void kernel_launch(void* const* d_in, const int* in_sizes, int n_in,
                              void* d_out, int out_size, void* d_ws, size_t ws_size,
                              hipStream_t stream) {
  const float* x = (const float*)d_in[0];     // [16384, 512]
  const float* e = (const float*)d_in[1];     // [8192, 512]
  float* out = (float*)d_out;

  char* ws = (char*)d_ws;
  // region A (0..16MB): xb during conv/dist; candidate worklists alias it afterwards
  ushort_t* xb = (ushort_t*)ws;                       // 16 MB
  int* candrows = (int*)ws;                           // 64 KB
  int* candn = (int*)(ws + 65536);                    // 64 KB
  int* candbuf = (int*)(ws + 131072);                 // 1 MB
  int* fullrows = (int*)(ws + 1179648);               // 64 KB
  int* counters = (int*)(ws + 1245184);               // 8 B
  ushort_t* eb = (ushort_t*)(ws + 16777216);          // 8 MB
  float* ehs = (float*)(ws + 25165824);               // 32 KB
  float4* pp = (float4*)(ws + 25198592);              // 16 MB -> ends 41975808

  conv_x<<<4096, 256, 0, stream>>>(x, xb);
  conv_e<<<2048, 256, 0, stream>>>(e, eb, ehs);
  dist_mfma<<<dim3(128, 64), 256, 0, stream>>>(xb, eb, ehs, pp);
  init_ws<<<1, 64, 0, stream>>>(counters);            // after dist_mfma: counters alias xb
  combine<<<4096, 256, 0, stream>>>(pp, e, out, candrows, candn, candbuf, fullrows, counters);
  cand_rescore<<<4096, 256, 0, stream>>>(x, e, ehs, candrows, candn, candbuf, counters, out);
  fb_full<<<64, 256, 0, stream>>>(x, e, ehs, fullrows, counters, out);
}

// Round 5
// 452.086 us; speedup vs baseline: 5.0835x; 5.0835x over previous
//
#include <hip/hip_runtime.h>
#include <cstddef>
#include <cstdint>

typedef unsigned short ushort_t;
typedef __attribute__((ext_vector_type(8))) short short8;
typedef __attribute__((ext_vector_type(4))) float f32x4;

constexpr int D_ = 512, K_ = 8192, N_ = 16384;
constexpr float MARGIN = 0.75f;   // ~15 sigma of bf16 score-noise difference

// RNE float->bf16 (data has no NaN)
__device__ __forceinline__ ushort_t f2bf(float f) {
  unsigned u = __float_as_uint(f);
  return (ushort_t)((u + 0x7FFFu + ((u >> 16) & 1u)) >> 16);
}

__device__ __forceinline__ void gld16(void* l, const void* g) {
  __builtin_amdgcn_global_load_lds((const __attribute__((address_space(1))) void*)g,
                                   (__attribute__((address_space(3))) void*)l, 16, 0, 0);
}

// -------- zero worklist counters + fbbest (runs AFTER dist_mfma; aliases xb) --------
__global__ __launch_bounds__(256) void init_ws(int* counters, unsigned long long* fbbest) {
  int t = blockIdx.x * 256 + threadIdx.x;   // grid 64*256 == N_
  fbbest[t] = 0ull;
  if (t < 2) counters[t] = 0;
}

// -------- convert x -> bf16 --------
__global__ __launch_bounds__(256) void conv_x(const float* __restrict__ x, ushort_t* __restrict__ xb) {
  int t = blockIdx.x * 256 + threadIdx.x;
  const float4* p = (const float4*)x;
  float4 a = p[t * 2], b = p[t * 2 + 1];
  short8 v;
  v[0] = (short)f2bf(a.x); v[1] = (short)f2bf(a.y); v[2] = (short)f2bf(a.z); v[3] = (short)f2bf(a.w);
  v[4] = (short)f2bf(b.x); v[5] = (short)f2bf(b.y); v[6] = (short)f2bf(b.z); v[7] = (short)f2bf(b.w);
  *(short8*)(xb + (size_t)t * 8) = v;
}

// -------- convert embed -> bf16, ehs = 0.5*||e||^2 (fp32) --------
__global__ __launch_bounds__(256) void conv_e(const float* __restrict__ e, ushort_t* __restrict__ eb,
                                              float* __restrict__ ehs) {
  int w = (blockIdx.x * 256 + threadIdx.x) >> 6;
  int l = threadIdx.x & 63;
  const float4* p = (const float4*)(e + (size_t)w * D_);
  float4 a = p[l * 2], b = p[l * 2 + 1];
  float s = a.x * a.x + a.y * a.y + a.z * a.z + a.w * a.w
          + b.x * b.x + b.y * b.y + b.z * b.z + b.w * b.w;
  short8 v;
  v[0] = (short)f2bf(a.x); v[1] = (short)f2bf(a.y); v[2] = (short)f2bf(a.z); v[3] = (short)f2bf(a.w);
  v[4] = (short)f2bf(b.x); v[5] = (short)f2bf(b.y); v[6] = (short)f2bf(b.z); v[7] = (short)f2bf(b.w);
  *(short8*)(eb + (size_t)w * D_ + l * 8) = v;
#pragma unroll
  for (int off = 32; off; off >>= 1) s += __shfl_xor(s, off);
  if (l == 0) ehs[w] = 0.5f * s;
}

// -------- MFMA scoring: per (row, 128-col block) top-2 (+indices) and margin count --------
// grid (N_/128, K_/128), 256 threads (2x2 waves, 64x64 per wave)
__global__ __launch_bounds__(256, 3) void dist_mfma(const ushort_t* __restrict__ xb,
                                                    const ushort_t* __restrict__ eb,
                                                    const float* __restrict__ ehs,
                                                    float4* __restrict__ pp) {
  __shared__ alignas(16) char lds[16384];
  char* As = lds;            // [kq(4)][row(128)] 16B chunks
  char* Bs = lds + 8192;
  const int tid = threadIdx.x, w = tid >> 6, l = tid & 63;
  const int row0 = blockIdx.x * 128, col0 = blockIdx.y * 128;
  const int wr = w >> 1, wc = w & 1;

  f32x4 acc[4][4] = {};
  for (int d0 = 0; d0 < D_; d0 += 32) {
#pragma unroll
    for (int i = 0; i < 2; ++i) {
      gld16(As + w * 2048 + i * 1024, xb + (size_t)(row0 + i * 64 + l) * D_ + d0 + w * 8);
      gld16(Bs + w * 2048 + i * 1024, eb + (size_t)(col0 + i * 64 + l) * D_ + d0 + w * 8);
    }
    __syncthreads();
    short8 a[4], b[4];
#pragma unroll
    for (int i = 0; i < 4; ++i)
      a[i] = *(const short8*)(As + (l >> 4) * 2048 + (wr * 64 + i * 16 + (l & 15)) * 16);
#pragma unroll
    for (int j = 0; j < 4; ++j)
      b[j] = *(const short8*)(Bs + (l >> 4) * 2048 + (wc * 64 + j * 16 + (l & 15)) * 16);
#pragma unroll
    for (int i = 0; i < 4; ++i)
#pragma unroll
      for (int j = 0; j < 4; ++j)
        acc[i][j] = __builtin_amdgcn_mfma_f32_16x16x32_bf16(a[i], b[j], acc[i][j], 0, 0, 0);
    __syncthreads();
  }

  // ---- epilogue pass 1: per-wave per-row top-2 (scores fp32 = acc - ehs) ----
  int colg[4];
  float eh[4];
#pragma unroll
  for (int j = 0; j < 4; ++j) { colg[j] = col0 + wc * 64 + j * 16 + (l & 15); eh[j] = ehs[colg[j]]; }

  const int c = l & 15, g = l >> 4;
  float fs1 = -3e38f, fs2 = -3e38f;
  int fi1 = 0, fi2 = 0;

#pragma unroll
  for (int i = 0; i < 4; ++i) {
    float s1v[4], s2v[4];
    int i1v[4], i2v[4];
#pragma unroll
    for (int r = 0; r < 4; ++r) {
      s1v[r] = -3e38f; s2v[r] = -3e38f; i1v[r] = 0; i2v[r] = 0;
#pragma unroll
      for (int j = 0; j < 4; ++j) {          // ascending cols -> strict '>' keeps min idx
        float v = acc[i][j][r] - eh[j];
        int col = colg[j];
        if (v > s1v[r]) { s2v[r] = s1v[r]; i2v[r] = i1v[r]; s1v[r] = v; i1v[r] = col; }
        else if (v > s2v[r]) { s2v[r] = v; i2v[r] = col; }
      }
    }
#pragma unroll
    for (int m = 1; m < 16; m <<= 1) {
#pragma unroll
      for (int r = 0; r < 4; ++r) {
        float os1 = __shfl_xor(s1v[r], m), os2 = __shfl_xor(s2v[r], m);
        int oi1 = __shfl_xor(i1v[r], m), oi2 = __shfl_xor(i2v[r], m);
        if (os1 > s1v[r] || (os1 == s1v[r] && oi1 < i1v[r])) {
          if (s1v[r] > os2 || (s1v[r] == os2 && i1v[r] < oi2)) { s2v[r] = s1v[r]; i2v[r] = i1v[r]; }
          else { s2v[r] = os2; i2v[r] = oi2; }
          s1v[r] = os1; i1v[r] = oi1;
        } else {
          if (os1 > s2v[r] || (os1 == s2v[r] && oi1 < i2v[r])) { s2v[r] = os1; i2v[r] = oi1; }
        }
      }
    }
    if ((c >> 2) == i) {
      int rsel = c & 3;
      fs1 = (rsel == 0) ? s1v[0] : (rsel == 1) ? s1v[1] : (rsel == 2) ? s1v[2] : s1v[3];
      fs2 = (rsel == 0) ? s2v[0] : (rsel == 1) ? s2v[1] : (rsel == 2) ? s2v[2] : s2v[3];
      fi1 = (rsel == 0) ? i1v[0] : (rsel == 1) ? i1v[1] : (rsel == 2) ? i1v[2] : i1v[3];
      fi2 = (rsel == 0) ? i2v[0] : (rsel == 1) ? i2v[1] : (rsel == 2) ? i2v[2] : i2v[3];
    }
  }
  const int rib = wr * 64 + (c >> 2) * 16 + g * 4 + (c & 3);   // lane's owned row in [0,128)

  // publish per-wave top-2 so all lanes can see the BLOCK top-1 (staging LDS is dead)
  float* ss1 = (float*)lds;          // [2][128] indexed wc*128+rib
  float* ss2 = ss1 + 256;
  int* si1 = (int*)(ss2 + 256);
  int* si2 = si1 + 256;
  int* scnt = si2 + 256;
  ss1[wc * 128 + rib] = fs1; ss2[wc * 128 + rib] = fs2;
  si1[wc * 128 + rib] = fi1; si2[wc * 128 + rib] = fi2;
  __syncthreads();

  // ---- pass 2: count scores >= block_top1 - MARGIN (sound overflow detector) ----
  int fcnt = 0;
#pragma unroll
  for (int i = 0; i < 4; ++i) {
    float thr[4];
#pragma unroll
    for (int r = 0; r < 4; ++r) {
      int row = wr * 64 + i * 16 + g * 4 + r;
      thr[r] = fmaxf(ss1[row], ss1[128 + row]) - MARGIN;
    }
    int cv[4];
#pragma unroll
    for (int r = 0; r < 4; ++r) {
      cv[r] = 0;
#pragma unroll
      for (int j = 0; j < 4; ++j)
        cv[r] += (acc[i][j][r] - eh[j] >= thr[r]) ? 1 : 0;
    }
#pragma unroll
    for (int m = 1; m < 16; m <<= 1)
#pragma unroll
      for (int r = 0; r < 4; ++r) cv[r] += __shfl_xor(cv[r], m);
    if ((c >> 2) == i) {
      int rsel = c & 3;
      fcnt = (rsel == 0) ? cv[0] : (rsel == 1) ? cv[1] : (rsel == 2) ? cv[2] : cv[3];
    }
  }
  scnt[wc * 128 + rib] = fcnt;
  __syncthreads();

  // ---- cross-wave merge + emit ----
  if (wc == 0) {
    float os1 = ss1[128 + rib], os2 = ss2[128 + rib];
    int oi1 = si1[128 + rib], oi2 = si2[128 + rib];
    int cc = fcnt + scnt[128 + rib];
    if (os1 > fs1 || (os1 == fs1 && oi1 < fi1)) {
      if (fs1 > os2 || (fs1 == os2 && fi1 < oi2)) { fs2 = fs1; fi2 = fi1; }
      else { fs2 = os2; fi2 = oi2; }
      fs1 = os1; fi1 = oi1;
    } else {
      if (os1 > fs2 || (os1 == fs2 && oi1 < fi2)) { fs2 = os1; fi2 = oi1; }
    }
    if (cc > 15) cc = 15;
    pp[(size_t)(row0 + rib) * 64 + blockIdx.y] =
        make_float4(fs1, __int_as_float(fi1 | (cc << 16)), fs2, __int_as_float(fi2));
  }
}

// -------- combine partials; decide, or emit candidate list / full-rescore list --------
__global__ __launch_bounds__(256) void combine(const float4* __restrict__ pp,
                                               const float* __restrict__ embed,
                                               float* __restrict__ out,
                                               int* __restrict__ candrows, int* __restrict__ candn,
                                               int* __restrict__ candbuf,
                                               int* __restrict__ fullrows, int* __restrict__ counters) {
  int row = (blockIdx.x * 256 + threadIdx.x) >> 6;
  int l = threadIdx.x & 63;
  float4 v = pp[(size_t)row * 64 + l];
  float s1 = v.x;
  int p1 = __float_as_int(v.y);
  int i1 = p1 & 0xFFFF;
  int cnt = p1 >> 16;
  float s2 = v.z;
  int i2 = __float_as_int(v.w);

  float gs = s1; int gi = i1;
#pragma unroll
  for (int m = 1; m < 64; m <<= 1) {
    float og = __shfl_xor(gs, m);
    int oi = __shfl_xor(gi, m);
    if (og > gs || (og == gs && oi < gi)) { gs = og; gi = oi; }
  }
  float t = gs - MARGIN;
  bool c1 = (s1 >= t);
  bool c2 = (s2 >= t);
  bool ovf = c1 && (cnt >= 3);     // block's 3rd-best might also be >= t
  unsigned long long b1 = __ballot(c1);
  unsigned long long b2 = __ballot(c2);
  unsigned long long bo = __ballot(ovf);
  int n1 = __popcll(b1);
  int ncand = n1 + __popcll(b2);

  if (bo == 0ull && ncand == 1) {
    const float4* src = (const float4*)(embed + (size_t)gi * D_);
    float4* dst = (float4*)(out + (size_t)row * D_);
    dst[l] = src[l];
    dst[l + 64] = src[l + 64];
    if (l == 0) out[(size_t)N_ * D_ + row] = (float)gi;
  } else if (bo == 0ull && ncand <= 16) {
    int slot;
    if (l == 0) slot = atomicAdd(&counters[0], 1);
    slot = __shfl(slot, 0);
    if (l == 0) { candrows[slot] = row; candn[slot] = ncand; }
    unsigned long long below = (1ull << l) - 1ull;
    if (c1) candbuf[slot * 16 + __popcll(b1 & below)] = i1;
    if (c2) candbuf[slot * 16 + n1 + __popcll(b2 & below)] = i2;
  } else {
    if (l == 0) {
      int fs = atomicAdd(&counters[1], 1);
      fullrows[fs] = row;
    }
  }
}

// -------- exact fp32 rescore of candidate columns: one wave per flagged row --------
__global__ __launch_bounds__(256) void cand_rescore(const float* __restrict__ x,
                                                    const float* __restrict__ embed,
                                                    const float* __restrict__ ehs,
                                                    const int* __restrict__ candrows,
                                                    const int* __restrict__ candn,
                                                    const int* __restrict__ candbuf,
                                                    const int* __restrict__ counters,
                                                    float* __restrict__ out) {
  int slot = (blockIdx.x * 256 + threadIdx.x) >> 6;
  int l = threadIdx.x & 63;
  if (slot >= counters[0]) return;
  int row = candrows[slot];
  int nc = candn[slot];
  float4 xa = *(const float4*)(x + (size_t)row * D_ + l * 8);
  float4 xc = *(const float4*)(x + (size_t)row * D_ + l * 8 + 4);
  float bs = -3e38f;
  int bi = 0x7fffffff;
  for (int cI = 0; cI < nc; ++cI) {
    int col = candbuf[slot * 16 + cI];
    float4 ea = *(const float4*)(embed + (size_t)col * D_ + l * 8);
    float4 ec = *(const float4*)(embed + (size_t)col * D_ + l * 8 + 4);
    float s = xa.x * ea.x + xa.y * ea.y + xa.z * ea.z + xa.w * ea.w
            + xc.x * ec.x + xc.y * ec.y + xc.z * ec.z + xc.w * ec.w;
#pragma unroll
    for (int m = 1; m < 64; m <<= 1) s += __shfl_xor(s, m);
    s -= ehs[col];
    if (s > bs || (s == bs && col < bi)) { bs = s; bi = col; }
  }
  const float4* src = (const float4*)(embed + (size_t)bi * D_);
  float4* dst = (float4*)(out + (size_t)row * D_);
  dst[l] = src[l];
  dst[l + 64] = src[l + 64];
  if (l == 0) out[(size_t)N_ * D_ + row] = (float)bi;
}

// -------- parallel full fp32 rescore for overflow rows (expected ~200 rows) --------
// grid (64 row-slots grid-strided, 8 col-chunks of 1024), 256 threads, 4 cols/thread
__global__ __launch_bounds__(256) void fb_full(const float* __restrict__ x,
                                               const float* __restrict__ embed,
                                               const float* __restrict__ ehs,
                                               const int* __restrict__ fullrows,
                                               const int* __restrict__ counters,
                                               unsigned long long* __restrict__ fbbest) {
  int nfull = counters[1];
  const int c0 = blockIdx.y * 1024 + threadIdx.x;
  __shared__ float xs[512];
  __shared__ unsigned long long red[4];
  for (int s = blockIdx.x; s < nfull; s += gridDim.x) {
    int row = fullrows[s];
    __syncthreads();   // protect xs/red reuse across iterations
    for (int q = threadIdx.x; q < 128; q += 256)
      ((float4*)xs)[q] = ((const float4*)(x + (size_t)row * D_))[q];
    __syncthreads();
    float a0 = 0.f, a1 = 0.f, a2 = 0.f, a3 = 0.f;
    const float* e0 = embed + (size_t)c0 * D_;
    const float* e1 = embed + (size_t)(c0 + 256) * D_;
    const float* e2 = embed + (size_t)(c0 + 512) * D_;
    const float* e3 = embed + (size_t)(c0 + 768) * D_;
    for (int d = 0; d < D_; d += 4) {
      float4 xv = *(const float4*)(&xs[d]);
      float4 v0 = *(const float4*)(e0 + d);
      float4 v1 = *(const float4*)(e1 + d);
      float4 v2 = *(const float4*)(e2 + d);
      float4 v3 = *(const float4*)(e3 + d);
      a0 = fmaf(v0.x, xv.x, fmaf(v0.y, xv.y, fmaf(v0.z, xv.z, fmaf(v0.w, xv.w, a0))));
      a1 = fmaf(v1.x, xv.x, fmaf(v1.y, xv.y, fmaf(v1.z, xv.z, fmaf(v1.w, xv.w, a1))));
      a2 = fmaf(v2.x, xv.x, fmaf(v2.y, xv.y, fmaf(v2.z, xv.z, fmaf(v2.w, xv.w, a2))));
      a3 = fmaf(v3.x, xv.x, fmaf(v3.y, xv.y, fmaf(v3.z, xv.z, fmaf(v3.w, xv.w, a3))));
    }
    float b = a0 - ehs[c0];
    int bi = c0;
    float sv;
    sv = a1 - ehs[c0 + 256]; if (sv > b) { b = sv; bi = c0 + 256; }
    sv = a2 - ehs[c0 + 512]; if (sv > b) { b = sv; bi = c0 + 512; }
    sv = a3 - ehs[c0 + 768]; if (sv > b) { b = sv; bi = c0 + 768; }
    unsigned ub = __float_as_uint(b);
    unsigned mb = (ub & 0x80000000u) ? ~ub : (ub | 0x80000000u);
    unsigned long long packed = ((unsigned long long)mb << 32) | (0xFFFFFFFFu - (unsigned)bi);
#pragma unroll
    for (int m = 1; m < 64; m <<= 1) {
      unsigned long long o = __shfl_xor(packed, m);
      if (o > packed) packed = o;
    }
    if ((threadIdx.x & 63) == 0) red[threadIdx.x >> 6] = packed;
    __syncthreads();
    if (threadIdx.x == 0) {
      unsigned long long p0 = red[0] > red[1] ? red[0] : red[1];
      unsigned long long p1 = red[2] > red[3] ? red[2] : red[3];
      unsigned long long p = p0 > p1 ? p0 : p1;
      atomicMax(&fbbest[row], p);
    }
  }
}

// -------- write outputs for overflow rows --------
__global__ __launch_bounds__(256) void fb_final(const float* __restrict__ embed,
                                                const int* __restrict__ fullrows,
                                                const int* __restrict__ counters,
                                                const unsigned long long* __restrict__ fbbest,
                                                float* __restrict__ out) {
  int slot = (blockIdx.x * 256 + threadIdx.x) >> 6;
  int l = threadIdx.x & 63;
  if (slot >= counters[1]) return;
  int row = fullrows[slot];
  unsigned long long p = fbbest[row];
  int idx = (int)(0xFFFFFFFFu - (unsigned)(p & 0xFFFFFFFFu));
  const float4* src = (const float4*)(embed + (size_t)idx * D_);
  float4* dst = (float4*)(out + (size_t)row * D_);
  dst[l] = src[l];
  dst[l + 64] = src[l + 64];
  if (l == 0) out[(size_t)N_ * D_ + row] = (float)idx;
}

extern "C" void kernel_launch(void* const* d_in, const int* in_sizes, int n_in,
                              void* d_out, int out_size, void* d_ws, size_t ws_size,
                              hipStream_t stream) {
  const float* x = (const float*)d_in[0];     // [16384, 512]
  const float* e = (const float*)d_in[1];     // [8192, 512]
  float* out = (float*)d_out;

  char* ws = (char*)d_ws;
  // region A (0..16MB): xb during conv/dist; worklists alias it afterwards
  ushort_t* xb = (ushort_t*)ws;                                     // 16 MB
  int* candrows = (int*)ws;                                         // 64 KB
  int* candn = (int*)(ws + 65536);                                  // 64 KB
  int* candbuf = (int*)(ws + 131072);                               // 1 MB
  int* fullrows = (int*)(ws + 1179648);                             // 64 KB
  int* counters = (int*)(ws + 1245184);                             // 8 B
  unsigned long long* fbbest = (unsigned long long*)(ws + 1310720); // 128 KB
  ushort_t* eb = (ushort_t*)(ws + 16777216);                        // 8 MB
  float* ehs = (float*)(ws + 25165824);                             // 32 KB
  float4* pp = (float4*)(ws + 25198592);                            // 16 MB -> ends 41975808

  conv_x<<<4096, 256, 0, stream>>>(x, xb);
  conv_e<<<2048, 256, 0, stream>>>(e, eb, ehs);
  dist_mfma<<<dim3(128, 64), 256, 0, stream>>>(xb, eb, ehs, pp);
  init_ws<<<64, 256, 0, stream>>>(counters, fbbest);   // after dist_mfma: aliases xb
  combine<<<4096, 256, 0, stream>>>(pp, e, out, candrows, candn, candbuf, fullrows, counters);
  cand_rescore<<<4096, 256, 0, stream>>>(x, e, ehs, candrows, candn, candbuf, counters, out);
  fb_full<<<dim3(64, 8), 256, 0, stream>>>(x, e, ehs, fullrows, counters, fbbest);
  fb_final<<<4096, 256, 0, stream>>>(e, fullrows, counters, fbbest, out);
}